// Round 3
// baseline (503.828 us; speedup 1.0000x reference)
//
#include <hip/hip_runtime.h>
#include <hip/hip_bf16.h>
#include <stdint.h>

#define N_NODES 100000
#define N_EDGES 3200000
#define IN_F 256
#define HID 128
#define OUT_F 8

#define NB   391        // node buckets of 256
#define PASS 6144       // edges staged per k_part block (33KB LDS -> 4 blk/CU)
#define CAP  10240      // k_csr LDS stage capacity

typedef short short8 __attribute__((ext_vector_type(8)));
typedef float f32x4 __attribute__((ext_vector_type(4)));
typedef float f32x2 __attribute__((ext_vector_type(2)));

// bf16 pack helpers (RNE)
__device__ __forceinline__ uint32_t pk_bf16(float a, float b) {
    uint32_t ua = __float_as_uint(a);
    uint32_t ub = __float_as_uint(b);
    ua = (ua + 0x7fff + ((ua >> 16) & 1)) >> 16;
    ub = (ub + 0x7fff + ((ub >> 16) & 1)) & 0xffff0000u;
    return ua | ub;
}

// ---------------------------------------------------------------------------
// Bucket histogram (LDS-aggregated, int4 edge reads)
// ---------------------------------------------------------------------------
__global__ __launch_bounds__(256) void k_bhist(const int* __restrict__ dst,
                                               int* __restrict__ gcnt, int E) {
    __shared__ int lb[NB];
    for (int i = threadIdx.x; i < NB; i += 256) lb[i] = 0;
    __syncthreads();
    int stride = gridDim.x * 256;
    const int4* d4 = (const int4*)dst;
    for (int e = blockIdx.x * 256 + threadIdx.x; e < E / 4; e += stride) {
        int4 d = d4[e];
        atomicAdd(&lb[d.x >> 8], 1);
        atomicAdd(&lb[d.y >> 8], 1);
        atomicAdd(&lb[d.z >> 8], 1);
        atomicAdd(&lb[d.w >> 8], 1);
    }
    __syncthreads();
    for (int i = threadIdx.x; i < NB; i += 256) {
        int c = lb[i];
        if (c) atomicAdd(&gcnt[i * 64], c);
    }
}

__global__ __launch_bounds__(512) void k_bscan(const int* __restrict__ gcnt,
                                               int* __restrict__ bbase,
                                               int* __restrict__ gcur) {
    __shared__ int sc[512];
    int tid = threadIdx.x;
    int v = (tid < NB) ? gcnt[tid * 64] : 0;
    sc[tid] = v;
    __syncthreads();
    for (int d = 1; d < 512; d <<= 1) {
        int t = (tid >= d) ? sc[tid - d] : 0;
        __syncthreads();
        sc[tid] += t;
        __syncthreads();
    }
    int excl = sc[tid] - v;
    if (tid <= NB) bbase[tid] = excl;
    if (tid < NB) gcur[tid * 64] = excl;
}

// ---------------------------------------------------------------------------
// Partition edges into bucket-contiguous regions (LDS-staged flush), 512 thr
// ---------------------------------------------------------------------------
__global__ __launch_bounds__(512) void k_part(const int* __restrict__ src,
                                              const int* __restrict__ dst,
                                              int* __restrict__ gcur,
                                              uint32_t* __restrict__ epk, int E) {
    __shared__ int lcnt[NB], loff[NB], ladj[NB], lcur[NB];
    __shared__ int sc[512];
    __shared__ uint32_t stage[PASS];
    int tid = threadIdx.x;
    int e0 = blockIdx.x * PASS;

    for (int i = tid; i < NB; i += 512) { lcnt[i] = 0; lcur[i] = 0; }
    __syncthreads();
    for (int i = tid; i < PASS; i += 512) {
        int e = e0 + i;
        if (e < E) atomicAdd(&lcnt[dst[e] >> 8], 1);
    }
    __syncthreads();
    int v = (tid < NB) ? lcnt[tid] : 0;
    sc[tid] = v;
    __syncthreads();
    for (int d = 1; d < 512; d <<= 1) {
        int t = (tid >= d) ? sc[tid - d] : 0;
        __syncthreads();
        sc[tid] += t;
        __syncthreads();
    }
    if (tid < NB) loff[tid] = sc[tid] - v;
    __syncthreads();
    if (tid < NB) {
        int len = lcnt[tid];
        if (len > 0) ladj[tid] = atomicAdd(&gcur[tid * 64], len);
    }
    __syncthreads();
    for (int i = tid; i < PASS; i += 512) {
        int e = e0 + i;
        if (e < E) {
            int d = dst[e];
            int b = d >> 8;
            int r = atomicAdd(&lcur[b], 1);
            stage[loff[b] + r] = (uint32_t)src[e] | ((uint32_t)(d & 255) << 17);
        }
    }
    __syncthreads();
    int wv = tid >> 6, ln = tid & 63;
    for (int b = wv; b < NB; b += 8) {
        int len = lcnt[b], lo = loff[b], gb = ladj[b];
        for (int j = ln; j < len; j += 64) epk[gb + j] = stage[lo + j];
    }
}

// ---------------------------------------------------------------------------
// Per-bucket CSR finalize: offs/cnt/dinv + node-sorted ssrc. 1024 threads.
// NEW: each node's edge list is additionally sorted by src id (insertion
// sort in LDS, 1 thread/node). All waves in k_agg1/k_agg2 then sweep src
// space in the same ascending order -> the gather working set becomes a
// sliding L2-resident window instead of a uniform-random 12.8 MB table.
// ---------------------------------------------------------------------------
__global__ __launch_bounds__(1024) void k_csr(const uint32_t* __restrict__ epk,
                                              const int* __restrict__ bbase,
                                              int* __restrict__ offs,
                                              int* __restrict__ cnt,
                                              float* __restrict__ dinv,
                                              int* __restrict__ ssrc, int N) {
    __shared__ int lcnt[256], lcur[256], loff[256];
    __shared__ uint32_t stage[CAP];
    int tid = threadIdx.x, b = blockIdx.x;
    int base = bbase[b], m = bbase[b + 1] - base;

    if (tid < 256) lcnt[tid] = 0;
    __syncthreads();
    for (int i = tid; i < m; i += 1024)
        atomicAdd(&lcnt[(epk[base + i] >> 17) & 255], 1);
    __syncthreads();
    int v = (tid < 256) ? lcnt[tid] : 0;
    if (tid < 256) loff[tid] = v;
    __syncthreads();
    for (int d = 1; d < 256; d <<= 1) {
        int t = (tid >= d && tid < 256) ? loff[tid - d] : 0;
        __syncthreads();
        if (tid < 256) loff[tid] += t;
        __syncthreads();
    }
    int excl = (tid < 256) ? (loff[tid] - v) : 0;
    __syncthreads();
    if (tid < 256) {
        loff[tid] = excl;
        lcur[tid] = 0;
        int node = b * 256 + tid;
        if (node < N) {
            offs[node] = base + excl;
            cnt[node] = v;
            dinv[node] = rsqrtf((float)(v + 1));
        }
    }
    __syncthreads();
    if (m <= CAP) {
        for (int i = tid; i < m; i += 1024) {
            uint32_t u = epk[base + i];
            int ld = (u >> 17) & 255;
            int r = atomicAdd(&lcur[ld], 1);
            stage[loff[ld] + r] = u & 0x1FFFF;
        }
        __syncthreads();
        // per-node insertion sort by src id (stage holds pure src values)
        if (tid < 256) {
            int lo = loff[tid], len = lcnt[tid];
            for (int i = 1; i < len; i++) {
                uint32_t key = stage[lo + i];
                int k2 = i - 1;
                while (k2 >= 0 && stage[lo + k2] > key) {
                    stage[lo + k2 + 1] = stage[lo + k2];
                    k2--;
                }
                stage[lo + k2 + 1] = key;
            }
        }
        __syncthreads();
        for (int i = tid; i < m; i += 1024) ssrc[base + i] = (int)stage[i];
    } else {
        // fallback (statistically unreachable: E[m]=8192, CAP=10240): unsorted
        for (int i = tid; i < m; i += 1024) {
            uint32_t u = epk[base + i];
            int ld = (u >> 17) & 255;
            int r = atomicAdd(&lcur[ld], 1);
            ssrc[base + loff[ld] + r] = (int)(u & 0x1FFFF);
        }
    }
}

// ---------------------------------------------------------------------------
// W1 [256][128] fp32 -> W1bf [128][256] bf16 (transposed, n-major)
// ---------------------------------------------------------------------------
__global__ __launch_bounds__(256) void k_wcast(const float* __restrict__ W1,
                                               ushort* __restrict__ Wbf) {
    __shared__ ushort T[128][33];
    int t = threadIdx.x;
    int k0 = blockIdx.x * 32;
    for (int idx = t; idx < 32 * 128; idx += 256) {
        int k = idx >> 7, n = idx & 127;
        uint32_t uv = __float_as_uint(W1[(size_t)(k0 + k) * HID + n]);
        uv = (uv + 0x7fff + ((uv >> 16) & 1)) >> 16;
        T[n][k] = (ushort)uv;
    }
    __syncthreads();
    for (int idx = t; idx < 32 * 128; idx += 256) {
        int n = idx >> 5, k = idx & 31;
        Wbf[(size_t)n * IN_F + k0 + k] = T[n][k];
    }
}

// ---------------------------------------------------------------------------
// GEMM1 (MFMA bf16): Hs8[100000][128](fp8 e4m3) = (X @ W1) * dinv[row]
// ---------------------------------------------------------------------------
__global__ __launch_bounds__(256) void k_gemm1(const float* __restrict__ X,
                                               const ushort* __restrict__ Wbf,
                                               const float* __restrict__ dinv,
                                               uint32_t* __restrict__ Hs8, int M) {
    __shared__ uint32_t As[64 * 20];    // 64 rows x 40 bf16
    __shared__ uint32_t Bs[128 * 20];   // 128 n-rows x 40 bf16
    __shared__ float st[4][16 * 132];   // per-wave epilogue stage
    int t = threadIdx.x;
    int lane = t & 63, w = t >> 6;
    int q = lane >> 4, c16 = lane & 15;
    int row0 = blockIdx.x * 64;

    int ar = t >> 2, a4 = (t & 3);
    int grow = row0 + ar; if (grow >= M) grow = M - 1;
    const float* xrow = X + (size_t)grow * IN_F;
    int bn = t >> 1, b1h = (t & 1);
    const ushort* wrow = Wbf + (size_t)bn * IN_F;

    f32x4 acc[8];
    #pragma unroll
    for (int j = 0; j < 8; j++) acc[j] = (f32x4){0.f, 0.f, 0.f, 0.f};

    for (int kc = 0; kc < IN_F; kc += 32) {
        float4 x0 = *(const float4*)(xrow + kc + a4 * 8);
        float4 x1 = *(const float4*)(xrow + kc + a4 * 8 + 4);
        uint4 wv0 = *(const uint4*)(wrow + kc + b1h * 16);
        uint4 wv1 = *(const uint4*)(wrow + kc + b1h * 16 + 8);
        __syncthreads();
        *(uint2*)&As[ar * 20 + a4 * 4]     = make_uint2(pk_bf16(x0.x, x0.y), pk_bf16(x0.z, x0.w));
        *(uint2*)&As[ar * 20 + a4 * 4 + 2] = make_uint2(pk_bf16(x1.x, x1.y), pk_bf16(x1.z, x1.w));
        *(uint4*)&Bs[bn * 20 + b1h * 8]     = wv0;
        *(uint4*)&Bs[bn * 20 + b1h * 8 + 4] = wv1;
        __syncthreads();
        short8 af = *(const short8*)&As[(w * 16 + c16) * 20 + q * 4];
        #pragma unroll
        for (int j = 0; j < 8; j++) {
            short8 bf = *(const short8*)&Bs[(j * 16 + c16) * 20 + q * 4];
            acc[j] = __builtin_amdgcn_mfma_f32_16x16x32_bf16(af, bf, acc[j], 0, 0, 0);
        }
    }
    float dv[4];
    #pragma unroll
    for (int r = 0; r < 4; r++) {
        int gr = row0 + w * 16 + q * 4 + r;
        dv[r] = (gr < M) ? dinv[gr] : 0.f;
    }
    #pragma unroll
    for (int j = 0; j < 8; j++)
        #pragma unroll
        for (int r = 0; r < 4; r++)
            st[w][(q * 4 + r) * 132 + j * 16 + c16] = acc[j][r] * dv[r];
    __syncthreads();
    #pragma unroll
    for (int p = 0; p < 4; p++) {
        int rr = p * 4 + q;
        int gr = row0 + w * 16 + rr;
        float4 v0 = *(const float4*)&st[w][rr * 132 + c16 * 8];
        float4 v1 = *(const float4*)&st[w][rr * 132 + c16 * 8 + 4];
        uint32_t lo = 0, hi = 0;
        lo = __builtin_amdgcn_cvt_pk_fp8_f32(v0.x, v0.y, lo, false);
        lo = __builtin_amdgcn_cvt_pk_fp8_f32(v0.z, v0.w, lo, true);
        hi = __builtin_amdgcn_cvt_pk_fp8_f32(v1.x, v1.y, hi, false);
        hi = __builtin_amdgcn_cvt_pk_fp8_f32(v1.z, v1.w, hi, true);
        if (gr < M) *(uint2*)&Hs8[(size_t)gr * 32 + c16 * 2] = make_uint2(lo, hi);
    }
}

// ---------------------------------------------------------------------------
// Aggregation layer 1 + ReLU + fused GEMM2: wave per node, fp8 rows (128B).
// Half-wave per edge, 8 loads in flight; packed f32x2 accumulate.
// After cross-half combine (both halves hold full sums), half h computes
// output feats [4h,4h+4) via LDS W2^T (float4 reads) + shuffle reduction.
// Writes h2s directly; a1 never materialized.
// ---------------------------------------------------------------------------
__global__ __launch_bounds__(256) void k_agg1(const uint32_t* __restrict__ hs,
                                              const int* __restrict__ offs,
                                              const int* __restrict__ cnt,
                                              const float* __restrict__ dinv,
                                              const int* __restrict__ ssrc,
                                              const float* __restrict__ b1,
                                              const float* __restrict__ W2,
                                              float* __restrict__ h2s, int N) {
    __shared__ float w2t[OUT_F * HID];   // transposed: w2t[f*128+k] = W2[k*8+f]
    int t = threadIdx.x;
    for (int i = t; i < OUT_F * HID; i += 256) {
        int f = i & 7, k = i >> 3;
        w2t[f * HID + k] = W2[k * OUT_F + f];
    }
    __syncthreads();
    int wid = (blockIdx.x * 256 + t) >> 6;
    int lane = t & 63;
    if (wid >= N) return;
    int h = lane >> 5, c = lane & 31;
    float dv = dinv[wid];
    f32x2 s01 = {0.f, 0.f}, s23 = {0.f, 0.f};
    if (h == 0) {
        uint32_t u = hs[(size_t)wid * 32 + c];
        s01 = __builtin_amdgcn_cvt_pk_f32_fp8(u, false);
        s23 = __builtin_amdgcn_cvt_pk_f32_fp8(u, true);
    }
    int beg = offs[wid], n = cnt[wid];
    const int* sp = ssrc + beg;
    int j = h;
    for (; j + 14 < n; j += 16) {
        int e0 = sp[j],      e1 = sp[j + 2],  e2 = sp[j + 4],  e3 = sp[j + 6];
        int e4 = sp[j + 8],  e5 = sp[j + 10], e6 = sp[j + 12], e7 = sp[j + 14];
        uint32_t u0 = hs[(size_t)e0 * 32 + c];
        uint32_t u1 = hs[(size_t)e1 * 32 + c];
        uint32_t u2 = hs[(size_t)e2 * 32 + c];
        uint32_t u3 = hs[(size_t)e3 * 32 + c];
        uint32_t u4 = hs[(size_t)e4 * 32 + c];
        uint32_t u5 = hs[(size_t)e5 * 32 + c];
        uint32_t u6 = hs[(size_t)e6 * 32 + c];
        uint32_t u7 = hs[(size_t)e7 * 32 + c];
        s01 += __builtin_amdgcn_cvt_pk_f32_fp8(u0, false); s23 += __builtin_amdgcn_cvt_pk_f32_fp8(u0, true);
        s01 += __builtin_amdgcn_cvt_pk_f32_fp8(u1, false); s23 += __builtin_amdgcn_cvt_pk_f32_fp8(u1, true);
        s01 += __builtin_amdgcn_cvt_pk_f32_fp8(u2, false); s23 += __builtin_amdgcn_cvt_pk_f32_fp8(u2, true);
        s01 += __builtin_amdgcn_cvt_pk_f32_fp8(u3, false); s23 += __builtin_amdgcn_cvt_pk_f32_fp8(u3, true);
        s01 += __builtin_amdgcn_cvt_pk_f32_fp8(u4, false); s23 += __builtin_amdgcn_cvt_pk_f32_fp8(u4, true);
        s01 += __builtin_amdgcn_cvt_pk_f32_fp8(u5, false); s23 += __builtin_amdgcn_cvt_pk_f32_fp8(u5, true);
        s01 += __builtin_amdgcn_cvt_pk_f32_fp8(u6, false); s23 += __builtin_amdgcn_cvt_pk_f32_fp8(u6, true);
        s01 += __builtin_amdgcn_cvt_pk_f32_fp8(u7, false); s23 += __builtin_amdgcn_cvt_pk_f32_fp8(u7, true);
    }
    for (; j + 6 < n; j += 8) {
        int e0 = sp[j], e1 = sp[j + 2], e2 = sp[j + 4], e3 = sp[j + 6];
        uint32_t u0 = hs[(size_t)e0 * 32 + c];
        uint32_t u1 = hs[(size_t)e1 * 32 + c];
        uint32_t u2 = hs[(size_t)e2 * 32 + c];
        uint32_t u3 = hs[(size_t)e3 * 32 + c];
        s01 += __builtin_amdgcn_cvt_pk_f32_fp8(u0, false); s23 += __builtin_amdgcn_cvt_pk_f32_fp8(u0, true);
        s01 += __builtin_amdgcn_cvt_pk_f32_fp8(u1, false); s23 += __builtin_amdgcn_cvt_pk_f32_fp8(u1, true);
        s01 += __builtin_amdgcn_cvt_pk_f32_fp8(u2, false); s23 += __builtin_amdgcn_cvt_pk_f32_fp8(u2, true);
        s01 += __builtin_amdgcn_cvt_pk_f32_fp8(u3, false); s23 += __builtin_amdgcn_cvt_pk_f32_fp8(u3, true);
    }
    for (; j < n; j += 2) {
        uint32_t u = hs[(size_t)sp[j] * 32 + c];
        s01 += __builtin_amdgcn_cvt_pk_f32_fp8(u, false);
        s23 += __builtin_amdgcn_cvt_pk_f32_fp8(u, true);
    }
    // combine halves (both halves end with identical full sums)
    s01[0] += __shfl_xor(s01[0], 32);
    s01[1] += __shfl_xor(s01[1], 32);
    s23[0] += __shfl_xor(s23[0], 32);
    s23[1] += __shfl_xor(s23[1], 32);
    // bias + ReLU (fp32, no bf16 round-trip)
    float4 bb = *(const float4*)(b1 + c * 4);
    float o0 = fmaxf(fmaf(s01[0], dv, bb.x), 0.f);
    float o1 = fmaxf(fmaf(s01[1], dv, bb.y), 0.f);
    float o2 = fmaxf(fmaf(s23[0], dv, bb.z), 0.f);
    float o3 = fmaxf(fmaf(s23[1], dv, bb.w), 0.f);
    // fused GEMM2 partial: half h computes feats f0..f0+3
    int f0 = h * 4;
    float p[4];
    #pragma unroll
    for (int f = 0; f < 4; f++) {
        float4 wv = *(const float4*)&w2t[(f0 + f) * HID + c * 4];
        p[f] = o0 * wv.x + o1 * wv.y + o2 * wv.z + o3 * wv.w;
    }
    #pragma unroll
    for (int d = 1; d < 32; d <<= 1) {
        #pragma unroll
        for (int f = 0; f < 4; f++) p[f] += __shfl_xor(p[f], d);
    }
    if (c == 0) {
        float4 ov = make_float4(p[0] * dv, p[1] * dv, p[2] * dv, p[3] * dv);
        *(float4*)&h2s[(size_t)wid * OUT_F + f0] = ov;
    }
}

// ---------------------------------------------------------------------------
// Aggregation layer 2 + bias + log_softmax, fused; 4-deep gather MLP.
// ---------------------------------------------------------------------------
__global__ __launch_bounds__(256) void k_agg2(const float* __restrict__ h2s,
                                              const int* __restrict__ offs,
                                              const int* __restrict__ cnt,
                                              const float* __restrict__ dinv,
                                              const int* __restrict__ ssrc,
                                              const float* __restrict__ b2,
                                              float* __restrict__ out, int N) {
    int wid = (blockIdx.x * 256 + threadIdx.x) >> 6;
    int lane = threadIdx.x & 63;
    if (wid >= N) return;
    int f = lane & 7, g = lane >> 3;
    float dv = dinv[wid];
    int beg = offs[wid], n = cnt[wid];
    const int* sp = ssrc + beg;
    float acc = 0.f;
    int j = g;
    for (; j + 24 < n; j += 32) {
        int s0 = sp[j], s1 = sp[j + 8], s2 = sp[j + 16], s3 = sp[j + 24];
        float v0 = h2s[(size_t)s0 * OUT_F + f];
        float v1 = h2s[(size_t)s1 * OUT_F + f];
        float v2 = h2s[(size_t)s2 * OUT_F + f];
        float v3 = h2s[(size_t)s3 * OUT_F + f];
        acc += v0 + v1 + v2 + v3;
    }
    for (; j < n; j += 8) acc += h2s[(size_t)sp[j] * OUT_F + f];
    acc += __shfl_xor(acc, 8);
    acc += __shfl_xor(acc, 16);
    acc += __shfl_xor(acc, 32);
    acc += h2s[(size_t)wid * OUT_F + f];
    acc = fmaf(acc, dv, b2[f]);
    float m = acc;
    m = fmaxf(m, __shfl_xor(m, 1));
    m = fmaxf(m, __shfl_xor(m, 2));
    m = fmaxf(m, __shfl_xor(m, 4));
    float e = expf(acc - m);
    float ssum = e;
    ssum += __shfl_xor(ssum, 1);
    ssum += __shfl_xor(ssum, 2);
    ssum += __shfl_xor(ssum, 4);
    float res = acc - m - logf(ssum);
    if (lane < 8) out[(size_t)wid * OUT_F + lane] = res;
}

// ---------------------------------------------------------------------------
extern "C" void kernel_launch(void* const* d_in, const int* in_sizes, int n_in,
                              void* d_out, int out_size, void* d_ws, size_t ws_size,
                              hipStream_t stream) {
    const float* x   = (const float*)d_in[0];
    const int*   ei  = (const int*)d_in[1];     // [2, E] flat: src then dst
    const float* W1  = (const float*)d_in[2];
    const float* b1  = (const float*)d_in[3];
    const float* W2  = (const float*)d_in[4];
    const float* b2  = (const float*)d_in[5];
    float* out = (float*)d_out;

    const int N = N_NODES, E = N_EDGES;
    const int* src = ei;
    const int* dst = ei + E;

    char* p = (char*)d_ws;
    auto carve = [&](size_t bytes) -> void* {
        void* r = (void*)p;
        p += (bytes + 511) & ~(size_t)511;
        return r;
    };
    int*      gcnt  = (int*)carve((size_t)NB * 64 * 4);
    int*      gcur  = (int*)carve((size_t)NB * 64 * 4);
    int*      bbase = (int*)carve((size_t)(NB + 1) * 4);
    uint32_t* epk   = (uint32_t*)carve((size_t)E * 4);
    int*      offs  = (int*)carve((size_t)N * 4);
    int*      cnt   = (int*)carve((size_t)N * 4);
    float*    dinv  = (float*)carve((size_t)N * 4);
    int*      ssrc  = (int*)carve((size_t)E * 4);
    ushort*   wbf   = (ushort*)carve((size_t)HID * IN_F * 2);
    uint32_t* hs8   = (uint32_t*)carve((size_t)N * 32 * 4);   // fp8 rows, 128B
    float*    h2s   = (float*)carve((size_t)N * OUT_F * 4);

    hipMemsetAsync(gcnt, 0, (size_t)NB * 64 * 4, stream);

    k_wcast<<<8, 256, 0, stream>>>(W1, wbf);
    k_bhist<<<512, 256, 0, stream>>>(dst, gcnt, E);
    k_bscan<<<1, 512, 0, stream>>>(gcnt, bbase, gcur);
    k_part<<<(E + PASS - 1) / PASS, 512, 0, stream>>>(src, dst, gcur, epk, E);
    k_csr<<<NB, 1024, 0, stream>>>(epk, bbase, offs, cnt, dinv, ssrc, N);

    k_gemm1<<<(N + 63) / 64, 256, 0, stream>>>(x, wbf, dinv, hs8, N);
    k_agg1<<<(N * 64 + 255) / 256, 256, 0, stream>>>(hs8, offs, cnt, dinv, ssrc, b1, W2, h2s, N);
    k_agg2<<<(N * 64 + 255) / 256, 256, 0, stream>>>(h2s, offs, cnt, dinv, ssrc, b2, out, N);
}

// Round 4
// 379.698 us; speedup vs baseline: 1.3269x; 1.3269x over previous
//
#include <hip/hip_runtime.h>
#include <hip/hip_bf16.h>
#include <stdint.h>

#define N_NODES 100000
#define N_EDGES 3200000
#define IN_F 256
#define HID 128
#define OUT_F 8

#define NB   391        // node buckets of 256
#define PASS 6144       // edges staged per k_part block (33KB LDS -> 4 blk/CU)
#define CAP  10240      // k_csr LDS stage capacity

typedef short short8 __attribute__((ext_vector_type(8)));
typedef float f32x4 __attribute__((ext_vector_type(4)));
typedef float f32x2 __attribute__((ext_vector_type(2)));

// bf16 pack helpers (RNE)
__device__ __forceinline__ uint32_t pk_bf16(float a, float b) {
    uint32_t ua = __float_as_uint(a);
    uint32_t ub = __float_as_uint(b);
    ua = (ua + 0x7fff + ((ua >> 16) & 1)) >> 16;
    ub = (ub + 0x7fff + ((ub >> 16) & 1)) & 0xffff0000u;
    return ua | ub;
}

// ---------------------------------------------------------------------------
// Bucket histogram (LDS-aggregated, int4 edge reads)
// ---------------------------------------------------------------------------
__global__ __launch_bounds__(256) void k_bhist(const int* __restrict__ dst,
                                               int* __restrict__ gcnt, int E) {
    __shared__ int lb[NB];
    for (int i = threadIdx.x; i < NB; i += 256) lb[i] = 0;
    __syncthreads();
    int stride = gridDim.x * 256;
    const int4* d4 = (const int4*)dst;
    for (int e = blockIdx.x * 256 + threadIdx.x; e < E / 4; e += stride) {
        int4 d = d4[e];
        atomicAdd(&lb[d.x >> 8], 1);
        atomicAdd(&lb[d.y >> 8], 1);
        atomicAdd(&lb[d.z >> 8], 1);
        atomicAdd(&lb[d.w >> 8], 1);
    }
    __syncthreads();
    for (int i = threadIdx.x; i < NB; i += 256) {
        int c = lb[i];
        if (c) atomicAdd(&gcnt[i * 64], c);
    }
}

__global__ __launch_bounds__(512) void k_bscan(const int* __restrict__ gcnt,
                                               int* __restrict__ bbase,
                                               int* __restrict__ gcur) {
    __shared__ int sc[512];
    int tid = threadIdx.x;
    int v = (tid < NB) ? gcnt[tid * 64] : 0;
    sc[tid] = v;
    __syncthreads();
    for (int d = 1; d < 512; d <<= 1) {
        int t = (tid >= d) ? sc[tid - d] : 0;
        __syncthreads();
        sc[tid] += t;
        __syncthreads();
    }
    int excl = sc[tid] - v;
    if (tid <= NB) bbase[tid] = excl;
    if (tid < NB) gcur[tid * 64] = excl;
}

// ---------------------------------------------------------------------------
// Partition edges into bucket-contiguous regions (LDS-staged flush), 512 thr
// ---------------------------------------------------------------------------
__global__ __launch_bounds__(512) void k_part(const int* __restrict__ src,
                                              const int* __restrict__ dst,
                                              int* __restrict__ gcur,
                                              uint32_t* __restrict__ epk, int E) {
    __shared__ int lcnt[NB], loff[NB], ladj[NB], lcur[NB];
    __shared__ int sc[512];
    __shared__ uint32_t stage[PASS];
    int tid = threadIdx.x;
    int e0 = blockIdx.x * PASS;

    for (int i = tid; i < NB; i += 512) { lcnt[i] = 0; lcur[i] = 0; }
    __syncthreads();
    for (int i = tid; i < PASS; i += 512) {
        int e = e0 + i;
        if (e < E) atomicAdd(&lcnt[dst[e] >> 8], 1);
    }
    __syncthreads();
    int v = (tid < NB) ? lcnt[tid] : 0;
    sc[tid] = v;
    __syncthreads();
    for (int d = 1; d < 512; d <<= 1) {
        int t = (tid >= d) ? sc[tid - d] : 0;
        __syncthreads();
        sc[tid] += t;
        __syncthreads();
    }
    if (tid < NB) loff[tid] = sc[tid] - v;
    __syncthreads();
    if (tid < NB) {
        int len = lcnt[tid];
        if (len > 0) ladj[tid] = atomicAdd(&gcur[tid * 64], len);
    }
    __syncthreads();
    for (int i = tid; i < PASS; i += 512) {
        int e = e0 + i;
        if (e < E) {
            int d = dst[e];
            int b = d >> 8;
            int r = atomicAdd(&lcur[b], 1);
            stage[loff[b] + r] = (uint32_t)src[e] | ((uint32_t)(d & 255) << 17);
        }
    }
    __syncthreads();
    int wv = tid >> 6, ln = tid & 63;
    for (int b = wv; b < NB; b += 8) {
        int len = lcnt[b], lo = loff[b], gb = ladj[b];
        for (int j = ln; j < len; j += 64) epk[gb + j] = stage[lo + j];
    }
}

// ---------------------------------------------------------------------------
// Per-bucket CSR finalize: offs/cnt/dinv + node-sorted ssrc. 1024 threads.
// ---------------------------------------------------------------------------
__global__ __launch_bounds__(1024) void k_csr(const uint32_t* __restrict__ epk,
                                              const int* __restrict__ bbase,
                                              int* __restrict__ offs,
                                              int* __restrict__ cnt,
                                              float* __restrict__ dinv,
                                              int* __restrict__ ssrc, int N) {
    __shared__ int lcnt[256], lcur[256], loff[256];
    __shared__ uint32_t stage[CAP];
    int tid = threadIdx.x, b = blockIdx.x;
    int base = bbase[b], m = bbase[b + 1] - base;

    if (tid < 256) lcnt[tid] = 0;
    __syncthreads();
    for (int i = tid; i < m; i += 1024)
        atomicAdd(&lcnt[(epk[base + i] >> 17) & 255], 1);
    __syncthreads();
    int v = (tid < 256) ? lcnt[tid] : 0;
    if (tid < 256) loff[tid] = v;
    __syncthreads();
    for (int d = 1; d < 256; d <<= 1) {
        int t = (tid >= d && tid < 256) ? loff[tid - d] : 0;
        __syncthreads();
        if (tid < 256) loff[tid] += t;
        __syncthreads();
    }
    int excl = (tid < 256) ? (loff[tid] - v) : 0;
    __syncthreads();
    if (tid < 256) {
        loff[tid] = excl;
        lcur[tid] = 0;
        int node = b * 256 + tid;
        if (node < N) {
            offs[node] = base + excl;
            cnt[node] = v;
            dinv[node] = rsqrtf((float)(v + 1));
        }
    }
    __syncthreads();
    if (m <= CAP) {
        for (int i = tid; i < m; i += 1024) {
            uint32_t u = epk[base + i];
            int ld = (u >> 17) & 255;
            int r = atomicAdd(&lcur[ld], 1);
            stage[loff[ld] + r] = u & 0x1FFFF;
        }
        __syncthreads();
        for (int i = tid; i < m; i += 1024) ssrc[base + i] = (int)stage[i];
    } else {
        for (int i = tid; i < m; i += 1024) {
            uint32_t u = epk[base + i];
            int ld = (u >> 17) & 255;
            int r = atomicAdd(&lcur[ld], 1);
            ssrc[base + loff[ld] + r] = (int)(u & 0x1FFFF);
        }
    }
}

// ---------------------------------------------------------------------------
// W1 [256][128] fp32 -> W1bf [128][256] bf16 (transposed, n-major)
// ---------------------------------------------------------------------------
__global__ __launch_bounds__(256) void k_wcast(const float* __restrict__ W1,
                                               ushort* __restrict__ Wbf) {
    __shared__ ushort T[128][33];
    int t = threadIdx.x;
    int k0 = blockIdx.x * 32;
    for (int idx = t; idx < 32 * 128; idx += 256) {
        int k = idx >> 7, n = idx & 127;
        uint32_t uv = __float_as_uint(W1[(size_t)(k0 + k) * HID + n]);
        uv = (uv + 0x7fff + ((uv >> 16) & 1)) >> 16;
        T[n][k] = (ushort)uv;
    }
    __syncthreads();
    for (int idx = t; idx < 32 * 128; idx += 256) {
        int n = idx >> 5, k = idx & 31;
        Wbf[(size_t)n * IN_F + k0 + k] = T[n][k];
    }
}

// ---------------------------------------------------------------------------
// GEMM1 (MFMA bf16): Hs8[100000][128](fp8 e4m3) = (X @ W1) * dinv[row]
// ---------------------------------------------------------------------------
__global__ __launch_bounds__(256) void k_gemm1(const float* __restrict__ X,
                                               const ushort* __restrict__ Wbf,
                                               const float* __restrict__ dinv,
                                               uint32_t* __restrict__ Hs8, int M) {
    __shared__ uint32_t As[64 * 20];    // 64 rows x 40 bf16
    __shared__ uint32_t Bs[128 * 20];   // 128 n-rows x 40 bf16
    __shared__ float st[4][16 * 132];   // per-wave epilogue stage
    int t = threadIdx.x;
    int lane = t & 63, w = t >> 6;
    int q = lane >> 4, c16 = lane & 15;
    int row0 = blockIdx.x * 64;

    int ar = t >> 2, a4 = (t & 3);
    int grow = row0 + ar; if (grow >= M) grow = M - 1;
    const float* xrow = X + (size_t)grow * IN_F;
    int bn = t >> 1, b1h = (t & 1);
    const ushort* wrow = Wbf + (size_t)bn * IN_F;

    f32x4 acc[8];
    #pragma unroll
    for (int j = 0; j < 8; j++) acc[j] = (f32x4){0.f, 0.f, 0.f, 0.f};

    for (int kc = 0; kc < IN_F; kc += 32) {
        float4 x0 = *(const float4*)(xrow + kc + a4 * 8);
        float4 x1 = *(const float4*)(xrow + kc + a4 * 8 + 4);
        uint4 wv0 = *(const uint4*)(wrow + kc + b1h * 16);
        uint4 wv1 = *(const uint4*)(wrow + kc + b1h * 16 + 8);
        __syncthreads();
        *(uint2*)&As[ar * 20 + a4 * 4]     = make_uint2(pk_bf16(x0.x, x0.y), pk_bf16(x0.z, x0.w));
        *(uint2*)&As[ar * 20 + a4 * 4 + 2] = make_uint2(pk_bf16(x1.x, x1.y), pk_bf16(x1.z, x1.w));
        *(uint4*)&Bs[bn * 20 + b1h * 8]     = wv0;
        *(uint4*)&Bs[bn * 20 + b1h * 8 + 4] = wv1;
        __syncthreads();
        short8 af = *(const short8*)&As[(w * 16 + c16) * 20 + q * 4];
        #pragma unroll
        for (int j = 0; j < 8; j++) {
            short8 bf = *(const short8*)&Bs[(j * 16 + c16) * 20 + q * 4];
            acc[j] = __builtin_amdgcn_mfma_f32_16x16x32_bf16(af, bf, acc[j], 0, 0, 0);
        }
    }
    float dv[4];
    #pragma unroll
    for (int r = 0; r < 4; r++) {
        int gr = row0 + w * 16 + q * 4 + r;
        dv[r] = (gr < M) ? dinv[gr] : 0.f;
    }
    #pragma unroll
    for (int j = 0; j < 8; j++)
        #pragma unroll
        for (int r = 0; r < 4; r++)
            st[w][(q * 4 + r) * 132 + j * 16 + c16] = acc[j][r] * dv[r];
    __syncthreads();
    #pragma unroll
    for (int p = 0; p < 4; p++) {
        int rr = p * 4 + q;
        int gr = row0 + w * 16 + rr;
        float4 v0 = *(const float4*)&st[w][rr * 132 + c16 * 8];
        float4 v1 = *(const float4*)&st[w][rr * 132 + c16 * 8 + 4];
        uint32_t lo = 0, hi = 0;
        lo = __builtin_amdgcn_cvt_pk_fp8_f32(v0.x, v0.y, lo, false);
        lo = __builtin_amdgcn_cvt_pk_fp8_f32(v0.z, v0.w, lo, true);
        hi = __builtin_amdgcn_cvt_pk_fp8_f32(v1.x, v1.y, hi, false);
        hi = __builtin_amdgcn_cvt_pk_fp8_f32(v1.z, v1.w, hi, true);
        if (gr < M) *(uint2*)&Hs8[(size_t)gr * 32 + c16 * 2] = make_uint2(lo, hi);
    }
}

// ---------------------------------------------------------------------------
// Aggregation layer 1 + ReLU + fused GEMM2: wave per node, fp8 rows (128B).
// Half-wave per edge, 8 row-loads per burst; SOFTWARE-PIPELINED index
// prefetch (batch k rows + batch k+1 indices simultaneously in flight) and
// dual independent accumulator chains (halved serial-add critical path).
// Epilogue unchanged from the verified 90.5 us version.
// ---------------------------------------------------------------------------
__global__ __launch_bounds__(256) void k_agg1(const uint32_t* __restrict__ hs,
                                              const int* __restrict__ offs,
                                              const int* __restrict__ cnt,
                                              const float* __restrict__ dinv,
                                              const int* __restrict__ ssrc,
                                              const float* __restrict__ b1,
                                              const float* __restrict__ W2,
                                              float* __restrict__ h2s, int N) {
    __shared__ float w2t[OUT_F * HID];   // transposed: w2t[f*128+k] = W2[k*8+f]
    int t = threadIdx.x;
    for (int i = t; i < OUT_F * HID; i += 256) {
        int f = i & 7, k = i >> 3;
        w2t[f * HID + k] = W2[k * OUT_F + f];
    }
    __syncthreads();
    int wid = (blockIdx.x * 256 + t) >> 6;
    int lane = t & 63;
    if (wid >= N) return;
    int h = lane >> 5, c = lane & 31;
    float dv = dinv[wid];
    // two independent accumulator chains (A, B)
    f32x2 a01 = {0.f, 0.f}, a23 = {0.f, 0.f};
    f32x2 g01 = {0.f, 0.f}, g23 = {0.f, 0.f};
    if (h == 0) {
        uint32_t u = hs[(size_t)wid * 32 + c];
        a01 = __builtin_amdgcn_cvt_pk_f32_fp8(u, false);
        a23 = __builtin_amdgcn_cvt_pk_f32_fp8(u, true);
    }
    int beg = offs[wid], n = cnt[wid];
    const int* sp = ssrc + beg;
#define ACCA(U) do { \
        a01 += __builtin_amdgcn_cvt_pk_f32_fp8((U), false); \
        a23 += __builtin_amdgcn_cvt_pk_f32_fp8((U), true);  \
    } while (0)
#define ACCB(U) do { \
        g01 += __builtin_amdgcn_cvt_pk_f32_fp8((U), false); \
        g23 += __builtin_amdgcn_cvt_pk_f32_fp8((U), true);  \
    } while (0)
    int j = h;
    if (j + 14 < n) {
        // prefetch batch 0 indices (all in range)
        int i0 = sp[j],      i1 = sp[j + 2],  i2 = sp[j + 4],  i3 = sp[j + 6];
        int i4 = sp[j + 8],  i5 = sp[j + 10], i6 = sp[j + 12], i7 = sp[j + 14];
        for (; j + 14 < n; j += 16) {
            // issue row loads for current batch
            uint32_t u0 = hs[(size_t)i0 * 32 + c];
            uint32_t u1 = hs[(size_t)i1 * 32 + c];
            uint32_t u2 = hs[(size_t)i2 * 32 + c];
            uint32_t u3 = hs[(size_t)i3 * 32 + c];
            uint32_t u4 = hs[(size_t)i4 * 32 + c];
            uint32_t u5 = hs[(size_t)i5 * 32 + c];
            uint32_t u6 = hs[(size_t)i6 * 32 + c];
            uint32_t u7 = hs[(size_t)i7 * 32 + c];
            // prefetch next batch indices (clamped; values only used if the
            // loop runs again, which requires all of them in range)
            int j2 = j + 16;
            int p0 = j2,      p1 = j2 + 2,  p2 = j2 + 4,  p3 = j2 + 6;
            int p4 = j2 + 8,  p5 = j2 + 10, p6 = j2 + 12, p7 = j2 + 14;
            i0 = sp[p0 < n ? p0 : j];
            i1 = sp[p1 < n ? p1 : j];
            i2 = sp[p2 < n ? p2 : j];
            i3 = sp[p3 < n ? p3 : j];
            i4 = sp[p4 < n ? p4 : j];
            i5 = sp[p5 < n ? p5 : j];
            i6 = sp[p6 < n ? p6 : j];
            i7 = sp[p7 < n ? p7 : j];
            // accumulate current batch on two independent chains
            ACCA(u0); ACCB(u1); ACCA(u2); ACCB(u3);
            ACCA(u4); ACCB(u5); ACCA(u6); ACCB(u7);
        }
    }
    for (; j + 6 < n; j += 8) {
        int e0 = sp[j], e1 = sp[j + 2], e2 = sp[j + 4], e3 = sp[j + 6];
        uint32_t u0 = hs[(size_t)e0 * 32 + c];
        uint32_t u1 = hs[(size_t)e1 * 32 + c];
        uint32_t u2 = hs[(size_t)e2 * 32 + c];
        uint32_t u3 = hs[(size_t)e3 * 32 + c];
        ACCA(u0); ACCB(u1); ACCA(u2); ACCB(u3);
    }
    for (; j < n; j += 2) {
        uint32_t u = hs[(size_t)sp[j] * 32 + c];
        ACCA(u);
    }
#undef ACCA
#undef ACCB
    // merge chains
    f32x2 s01 = a01 + g01;
    f32x2 s23 = a23 + g23;
    // combine halves (both halves end with identical full sums)
    s01[0] += __shfl_xor(s01[0], 32);
    s01[1] += __shfl_xor(s01[1], 32);
    s23[0] += __shfl_xor(s23[0], 32);
    s23[1] += __shfl_xor(s23[1], 32);
    // bias + ReLU (fp32, no bf16 round-trip)
    float4 bb = *(const float4*)(b1 + c * 4);
    float o0 = fmaxf(fmaf(s01[0], dv, bb.x), 0.f);
    float o1 = fmaxf(fmaf(s01[1], dv, bb.y), 0.f);
    float o2 = fmaxf(fmaf(s23[0], dv, bb.z), 0.f);
    float o3 = fmaxf(fmaf(s23[1], dv, bb.w), 0.f);
    // fused GEMM2 partial: half h computes feats f0..f0+3
    int f0 = h * 4;
    float p[4];
    #pragma unroll
    for (int f = 0; f < 4; f++) {
        float4 wv = *(const float4*)&w2t[(f0 + f) * HID + c * 4];
        p[f] = o0 * wv.x + o1 * wv.y + o2 * wv.z + o3 * wv.w;
    }
    #pragma unroll
    for (int d = 1; d < 32; d <<= 1) {
        #pragma unroll
        for (int f = 0; f < 4; f++) p[f] += __shfl_xor(p[f], d);
    }
    if (c == 0) {
        float4 ov = make_float4(p[0] * dv, p[1] * dv, p[2] * dv, p[3] * dv);
        *(float4*)&h2s[(size_t)wid * OUT_F + f0] = ov;
    }
}

// ---------------------------------------------------------------------------
// Aggregation layer 2 + bias + log_softmax, fused; 4-deep gather MLP.
// ---------------------------------------------------------------------------
__global__ __launch_bounds__(256) void k_agg2(const float* __restrict__ h2s,
                                              const int* __restrict__ offs,
                                              const int* __restrict__ cnt,
                                              const float* __restrict__ dinv,
                                              const int* __restrict__ ssrc,
                                              const float* __restrict__ b2,
                                              float* __restrict__ out, int N) {
    int wid = (blockIdx.x * 256 + threadIdx.x) >> 6;
    int lane = threadIdx.x & 63;
    if (wid >= N) return;
    int f = lane & 7, g = lane >> 3;
    float dv = dinv[wid];
    int beg = offs[wid], n = cnt[wid];
    const int* sp = ssrc + beg;
    float acc = 0.f;
    int j = g;
    for (; j + 24 < n; j += 32) {
        int s0 = sp[j], s1 = sp[j + 8], s2 = sp[j + 16], s3 = sp[j + 24];
        float v0 = h2s[(size_t)s0 * OUT_F + f];
        float v1 = h2s[(size_t)s1 * OUT_F + f];
        float v2 = h2s[(size_t)s2 * OUT_F + f];
        float v3 = h2s[(size_t)s3 * OUT_F + f];
        acc += v0 + v1 + v2 + v3;
    }
    for (; j < n; j += 8) acc += h2s[(size_t)sp[j] * OUT_F + f];
    acc += __shfl_xor(acc, 8);
    acc += __shfl_xor(acc, 16);
    acc += __shfl_xor(acc, 32);
    acc += h2s[(size_t)wid * OUT_F + f];
    acc = fmaf(acc, dv, b2[f]);
    float m = acc;
    m = fmaxf(m, __shfl_xor(m, 1));
    m = fmaxf(m, __shfl_xor(m, 2));
    m = fmaxf(m, __shfl_xor(m, 4));
    float e = expf(acc - m);
    float ssum = e;
    ssum += __shfl_xor(ssum, 1);
    ssum += __shfl_xor(ssum, 2);
    ssum += __shfl_xor(ssum, 4);
    float res = acc - m - logf(ssum);
    if (lane < 8) out[(size_t)wid * OUT_F + lane] = res;
}

// ---------------------------------------------------------------------------
extern "C" void kernel_launch(void* const* d_in, const int* in_sizes, int n_in,
                              void* d_out, int out_size, void* d_ws, size_t ws_size,
                              hipStream_t stream) {
    const float* x   = (const float*)d_in[0];
    const int*   ei  = (const int*)d_in[1];     // [2, E] flat: src then dst
    const float* W1  = (const float*)d_in[2];
    const float* b1  = (const float*)d_in[3];
    const float* W2  = (const float*)d_in[4];
    const float* b2  = (const float*)d_in[5];
    float* out = (float*)d_out;

    const int N = N_NODES, E = N_EDGES;
    const int* src = ei;
    const int* dst = ei + E;

    char* p = (char*)d_ws;
    auto carve = [&](size_t bytes) -> void* {
        void* r = (void*)p;
        p += (bytes + 511) & ~(size_t)511;
        return r;
    };
    int*      gcnt  = (int*)carve((size_t)NB * 64 * 4);
    int*      gcur  = (int*)carve((size_t)NB * 64 * 4);
    int*      bbase = (int*)carve((size_t)(NB + 1) * 4);
    uint32_t* epk   = (uint32_t*)carve((size_t)E * 4);
    int*      offs  = (int*)carve((size_t)N * 4);
    int*      cnt   = (int*)carve((size_t)N * 4);
    float*    dinv  = (float*)carve((size_t)N * 4);
    int*      ssrc  = (int*)carve((size_t)E * 4);
    ushort*   wbf   = (ushort*)carve((size_t)HID * IN_F * 2);
    uint32_t* hs8   = (uint32_t*)carve((size_t)N * 32 * 4);   // fp8 rows, 128B
    float*    h2s   = (float*)carve((size_t)N * OUT_F * 4);

    hipMemsetAsync(gcnt, 0, (size_t)NB * 64 * 4, stream);

    k_wcast<<<8, 256, 0, stream>>>(W1, wbf);
    k_bhist<<<512, 256, 0, stream>>>(dst, gcnt, E);
    k_bscan<<<1, 512, 0, stream>>>(gcnt, bbase, gcur);
    k_part<<<(E + PASS - 1) / PASS, 512, 0, stream>>>(src, dst, gcur, epk, E);
    k_csr<<<NB, 1024, 0, stream>>>(epk, bbase, offs, cnt, dinv, ssrc, N);

    k_gemm1<<<(N + 63) / 64, 256, 0, stream>>>(x, wbf, dinv, hs8, N);
    k_agg1<<<(N * 64 + 255) / 256, 256, 0, stream>>>(hs8, offs, cnt, dinv, ssrc, b1, W2, h2s, N);
    k_agg2<<<(N * 64 + 255) / 256, 256, 0, stream>>>(h2s, offs, cnt, dinv, ssrc, b2, out, N);
}